// Round 5
// baseline (116950.134 us; speedup 1.0000x reference)
//
#include <hip/hip_runtime.h>
#include <math.h>

#define TT   100000
#define HH   74
#define G4   296          // 4*H gate rows per layer
#define KH   40           // per-thread K half (padded 74 -> 80)
#define SLOT 80           // ring/LDS slot stride in floats (320 B, 16B aligned)
#define NT   704          // 10 row-waves (640 = 320 rows x 2 halves) + helper wave
#define W5   640

__global__ void init_ctrl(unsigned* ctrl) {
    if (threadIdx.x < 128) ctrl[threadIdx.x] = 0u;   // ws is poisoned 0xAA each launch
}

// min-waves-per-EU = 1: most permissive VGPR budget (512); the 11-wave block
// itself limits a SIMD to 3 waves -> >=170 VGPRs usable. Weights are NAMED
// float4s (SSA values), not arrays -> no PromoteAlloca involvement, no scratch.
__launch_bounds__(NT, 1)
__global__ void lstm_pipe(const float* __restrict__ seasons,
                          const float* __restrict__ W_ih,
                          const float* __restrict__ W_hh,
                          const float* __restrict__ b_ih,
                          const float* __restrict__ b_hh,
                          const float* __restrict__ W_lin,
                          const float* __restrict__ b_lin,
                          float* __restrict__ out,
                          unsigned* ctrl,
                          float* ring0, float* ring1, int C)
{
    const int stage = blockIdx.x;     // one workgroup per LSTM layer (pipeline stage)
    const int tid   = threadIdx.x;

    __shared__ __align__(16) float xbuf[2][SLOT];  // double-buffered layer input
    __shared__ __align__(16) float hbuf[SLOT];     // this layer's h_{t-1}
    __shared__ float gbuf[G4];                     // activated gates

    unsigned* cnt_out  = ctrl + stage * 32;
    unsigned* cnt_in   = ctrl + (stage > 0 ? (stage - 1) * 32 : 0);
    unsigned* cnt_down = ctrl + (stage < 2 ? (stage + 1) * 32 : 0);
    float* ring_out = (stage == 0) ? ring0 : ring1;
    float* ring_in  = (stage == 1) ? ring0 : ring1;

    // ---- LDS init: h_{-1}=0 (incl. pad), zero the pads of xbuf ----
    if (tid < SLOT) hbuf[tid] = 0.0f;
    if (tid >= SLOT && tid < SLOT + 2*(SLOT-HH)) {
        int k = tid - SLOT;
        xbuf[k/(SLOT-HH)][HH + k%(SLOT-HH)] = 0.0f;
    }

    // ---- row mapping: lane pair per row; each thread holds ONE K-half ----
    const bool isRowT = (tid < W5);
    const int  row  = (tid >> 6) * 32 + ((tid & 63) >> 1);   // 0..319 (>=296 pad)
    const int  half = tid & 1;                               // k-half
    const int  wrow = (row < G4) ? row : (G4 - 1);           // clamp for safe loads

    // 20 named float4 weight registers = 80 floats/thread (NOT arrays).
    float4 wi0={0,0,0,0},wi1={0,0,0,0},wi2={0,0,0,0},wi3={0,0,0,0},wi4={0,0,0,0},
           wi5={0,0,0,0},wi6={0,0,0,0},wi7={0,0,0,0},wi8={0,0,0,0},wi9={0,0,0,0};
    float4 wh0={0,0,0,0},wh1={0,0,0,0},wh2={0,0,0,0},wh3={0,0,0,0},wh4={0,0,0,0},
           wh5={0,0,0,0},wh6={0,0,0,0},wh7={0,0,0,0},wh8={0,0,0,0},wh9={0,0,0,0};
    float bias = 0.0f;

    if (isRowT) {
        const bool  isG = (wrow >= 2*HH) && (wrow < 3*HH);   // g-gate: fold tanh 2x
        const float sc  = isG ? 2.0f : 1.0f;
        const float* si = W_ih + (size_t)(stage*G4 + wrow) * HH;
        const float* sh = W_hh + (size_t)(stage*G4 + wrow) * HH;
#define LDW(V, P, Q) { \
        int k0 = half*KH + 4*(Q); \
        int ka=k0, kb=k0+1, kc=k0+2, kd=k0+3; \
        float va=(P)[ka<HH?ka:0], vb=(P)[kb<HH?kb:0]; \
        float vc=(P)[kc<HH?kc:0], vd=(P)[kd<HH?kd:0]; \
        V.x = ka<HH ? sc*va : 0.0f;  V.y = kb<HH ? sc*vb : 0.0f; \
        V.z = kc<HH ? sc*vc : 0.0f;  V.w = kd<HH ? sc*vd : 0.0f; }
        LDW(wi0,si,0) LDW(wi1,si,1) LDW(wi2,si,2) LDW(wi3,si,3) LDW(wi4,si,4)
        LDW(wi5,si,5) LDW(wi6,si,6) LDW(wi7,si,7) LDW(wi8,si,8) LDW(wi9,si,9)
        LDW(wh0,sh,0) LDW(wh1,sh,1) LDW(wh2,sh,2) LDW(wh3,sh,3) LDW(wh4,sh,4)
        LDW(wh5,sh,5) LDW(wh6,sh,6) LDW(wh7,sh,7) LDW(wh8,sh,8) LDW(wh9,sh,9)
#undef LDW
        if (half == 0)
            bias = sc * (b_ih[stage*G4 + wrow] + b_hh[stage*G4 + wrow]);
    }

    float wl0 = 0.f, wl1 = 0.f, blin = 0.f;
    if (stage == 2 && tid >= W5) {                 // final linear lives on helper wave
        int lane = tid - W5;
        wl0 = W_lin[lane];
        wl1 = (lane < HH-64) ? W_lin[64 + lane] : 0.0f;
        blin = b_lin[0];
    }

    __syncthreads();

    // ---- prologue (helper): xbuf[0] = x(0); xr = x(1) in regs ----
    float xr0 = 0.f, xr1 = 0.f;
    unsigned cin = 0, cons = 0;
    if (tid >= W5) {
        const int lane = tid - W5;
        if (stage == 0) {
            xbuf[0][lane] = seasons[lane];
            if (lane < HH-64) xbuf[0][64+lane] = seasons[64+lane];
            xr0 = seasons[HH + lane];
            if (lane < HH-64) xr1 = seasons[HH + 64 + lane];
        } else {
            do { cin = __hip_atomic_load(cnt_in, __ATOMIC_ACQUIRE, __HIP_MEMORY_SCOPE_AGENT); }
            while (cin < 2u);
            xbuf[0][lane] = __hip_atomic_load(ring_in + lane, __ATOMIC_RELAXED, __HIP_MEMORY_SCOPE_AGENT);
            if (lane < HH-64)
                xbuf[0][64+lane] = __hip_atomic_load(ring_in + 64 + lane, __ATOMIC_RELAXED, __HIP_MEMORY_SCOPE_AGENT);
            const float* rs = ring_in + (size_t)(1 % C) * SLOT;
            xr0 = __hip_atomic_load(rs + lane, __ATOMIC_RELAXED, __HIP_MEMORY_SCOPE_AGENT);
            if (lane < HH-64)
                xr1 = __hip_atomic_load(rs + 64 + lane, __ATOMIC_RELAXED, __HIP_MEMORY_SCOPE_AGENT);
        }
    }
    __syncthreads();

    float c = 0.0f;            // persistent cell state (tid < 74)
    float pf = 0.0f;           // L2 touch-prefetch sink

    for (int t = 0; t < TT; ++t) {
        // ================= Phase A =================
        if (isRowT) {
            // even lanes read float4s [0..9], odd lanes [10..19]: two distinct
            // addresses 160B apart -> 2-address access, conflict-free (m136)
            const float4* xv = ((const float4*)xbuf[t & 1]) + half*(KH/4);
            const float4* hv = ((const float4*)hbuf)        + half*(KH/4);
            float a0 = bias, a1 = 0.f, a2 = 0.f, a3 = 0.f;
#define ACC4(W, Vp, Q) { float4 v_ = (Vp)[Q]; \
            a0 = fmaf(W.x, v_.x, a0); a1 = fmaf(W.y, v_.y, a1); \
            a2 = fmaf(W.z, v_.z, a2); a3 = fmaf(W.w, v_.w, a3); }
            ACC4(wi0,xv,0) ACC4(wi1,xv,1) ACC4(wi2,xv,2) ACC4(wi3,xv,3) ACC4(wi4,xv,4)
            ACC4(wi5,xv,5) ACC4(wi6,xv,6) ACC4(wi7,xv,7) ACC4(wi8,xv,8) ACC4(wi9,xv,9)
            ACC4(wh0,hv,0) ACC4(wh1,hv,1) ACC4(wh2,hv,2) ACC4(wh3,hv,3) ACC4(wh4,hv,4)
            ACC4(wh5,hv,5) ACC4(wh6,hv,6) ACC4(wh7,hv,7) ACC4(wh8,hv,8) ACC4(wh9,hv,9)
#undef ACC4
            float p = (a0 + a1) + (a2 + a3);
            p += __shfl_xor(p, 1, 64);                       // combine K-halves
            float s = __builtin_amdgcn_rcpf(1.0f + __expf(-p));
            const bool isG = (row >= 2*HH) && (row < 3*HH);  // tanh = 2*sigm(2x)-1
            float g = isG ? fmaf(2.0f, s, -1.0f) : s;
            if (half == 0 && row < G4) gbuf[row] = g;
        } else {
            const int lane = tid - W5;
            // ---- ring store h(t-1) + publish (stages 0,1); linear (stage 2) ----
            if (t > 0) {
                if (stage < 2) {
                    float h0 = hbuf[lane];
                    float h1 = (lane < HH-64) ? hbuf[64+lane] : 0.0f;
                    while ((long)t - (long)cons > (long)(C - 8))     // flow control (rare)
                        cons = __hip_atomic_load(cnt_down, __ATOMIC_RELAXED, __HIP_MEMORY_SCOPE_AGENT);
                    float* rs = ring_out + (size_t)((t-1) % C) * SLOT;
                    __hip_atomic_store(rs + lane, h0, __ATOMIC_RELAXED, __HIP_MEMORY_SCOPE_AGENT);
                    if (lane < HH-64)
                        __hip_atomic_store(rs + 64 + lane, h1, __ATOMIC_RELAXED, __HIP_MEMORY_SCOPE_AGENT);
                    if (lane == 0)   // release waits this wave's stores -> visible first
                        __hip_atomic_store(cnt_out, (unsigned)t, __ATOMIC_RELEASE, __HIP_MEMORY_SCOPE_AGENT);
                } else {
                    if (lane == 0)   // progress only (stage1 flow control)
                        __hip_atomic_store(cnt_out, (unsigned)t, __ATOMIC_RELAXED, __HIP_MEMORY_SCOPE_AGENT);
                    float p = wl0 * hbuf[lane];
                    if (lane < HH-64) p += wl1 * hbuf[64 + lane];
                    #pragma unroll
                    for (int m = 32; m >= 1; m >>= 1)
                        p += __shfl_xor(p, m, 64);
                    if (lane == 0) out[t-1] = fmaxf(p + blin, 0.0f);
                }
            }
            // ---- write x(t+1) from regs (loaded one full step ago) ----
            const int nb = (t + 1) & 1;
            xbuf[nb][lane] = xr0;
            if (lane < HH-64) xbuf[nb][64+lane] = xr1;
            // ---- issue loads for x(t+2): latency spans a whole step ----
            if (t + 2 < TT) {
                if (stage == 0) {
                    const float* xs = seasons + (size_t)(t+2) * HH;
                    xr0 = xs[lane];
                    if (lane < HH-64) xr1 = xs[64+lane];
                    if (t + 16 < TT) pf += seasons[(size_t)(t+16)*HH + lane];
                } else {
                    if (cin < (unsigned)(t + 3)) {
                        do { cin = __hip_atomic_load(cnt_in, __ATOMIC_ACQUIRE, __HIP_MEMORY_SCOPE_AGENT); }
                        while (cin < (unsigned)(t + 3));
                    }
                    const float* rs2 = ring_in + (size_t)((t+2) % C) * SLOT;
                    xr0 = __hip_atomic_load(rs2 + lane, __ATOMIC_RELAXED, __HIP_MEMORY_SCOPE_AGENT);
                    if (lane < HH-64)
                        xr1 = __hip_atomic_load(rs2 + 64 + lane, __ATOMIC_RELAXED, __HIP_MEMORY_SCOPE_AGENT);
                    cin = __hip_atomic_load(cnt_in, __ATOMIC_RELAXED, __HIP_MEMORY_SCOPE_AGENT);
                }
            }
        }
        __syncthreads();   // barrier1: gates ready, x(t+1) staged

        // ================= Phase B =================
        if (tid < HH) {
            float iv = gbuf[tid];
            float fv = gbuf[HH + tid];
            float gv = gbuf[2*HH + tid];
            float ov = gbuf[3*HH + tid];
            c = fmaf(fv, c, iv * gv);
            float e  = __expf(-2.0f * fabsf(c));             // overflow-safe tanh
            float th = copysignf((1.0f - e) * __builtin_amdgcn_rcpf(1.0f + e), c);
            hbuf[tid] = ov * th;
        }
        __syncthreads();   // barrier2: h(t) ready
    }

    // ---- epilogue: h(TT-1) ----
    if (tid >= W5) {
        const int lane = tid - W5;
        if (stage < 2) {
            float h0 = hbuf[lane];
            float h1 = (lane < HH-64) ? hbuf[64+lane] : 0.0f;
            float* rs = ring_out + (size_t)((TT-1) % C) * SLOT;
            __hip_atomic_store(rs + lane, h0, __ATOMIC_RELAXED, __HIP_MEMORY_SCOPE_AGENT);
            if (lane < HH-64)
                __hip_atomic_store(rs + 64 + lane, h1, __ATOMIC_RELAXED, __HIP_MEMORY_SCOPE_AGENT);
            if (lane == 0)
                __hip_atomic_store(cnt_out, (unsigned)TT, __ATOMIC_RELEASE, __HIP_MEMORY_SCOPE_AGENT);
        } else {
            float p = wl0 * hbuf[lane];
            if (lane < HH-64) p += wl1 * hbuf[64 + lane];
            #pragma unroll
            for (int m = 32; m >= 1; m >>= 1)
                p += __shfl_xor(p, m, 64);
            if (lane == 0) out[TT-1] = fmaxf(p + blin, 0.0f);
        }
    }
    asm volatile("" :: "v"(pf));   // keep prefetch sum live
}

extern "C" void kernel_launch(void* const* d_in, const int* in_sizes, int n_in,
                              void* d_out, int out_size, void* d_ws, size_t ws_size,
                              hipStream_t stream)
{
    (void)in_sizes; (void)n_in; (void)out_size;
    const float* seasons = (const float*)d_in[0];
    const float* W_ih  = (const float*)d_in[1];
    const float* W_hh  = (const float*)d_in[2];
    const float* b_ih  = (const float*)d_in[3];
    const float* b_hh  = (const float*)d_in[4];
    const float* W_lin = (const float*)d_in[5];
    const float* b_lin = (const float*)d_in[6];
    float* out = (float*)d_out;

    unsigned* ctrl = (unsigned*)d_ws;
    float* ring0 = (float*)((char*)d_ws + 1024);
    long avail  = (long)ws_size - 1024;
    long cslots = avail / (long)(2 * SLOT * sizeof(float));
    int  C = (int)(cslots < TT ? cslots : TT);
    if (C > 2048) C = 2048;        // keep rings cache-resident
    if (C < 16)   C = 16;
    float* ring1 = ring0 + (size_t)C * SLOT;

    hipLaunchKernelGGL(init_ctrl, dim3(1), dim3(128), 0, stream, ctrl);
    hipLaunchKernelGGL(lstm_pipe, dim3(3), dim3(NT), 0, stream,
                       seasons, W_ih, W_hh, b_ih, b_hh, W_lin, b_lin,
                       out, ctrl, ring0, ring1, C);
}